// Round 10
// baseline (452.913 us; speedup 1.0000x reference)
//
#include <hip/hip_runtime.h>
#include <hip/hip_fp16.h>

// AdderNet forward:  x[256,1,64,64] -> adder(w1)+BN+ReLU -> adder(w2)+BN+ReLU
//                    -> avgpool -> FC -> out[256,10]
// R10: R9 with the stage-1 off-by-one fixed. R9's h1 tile uses x = col-2
// (68-col rows for 16B-aligned stage-2 reads) but stage-1 still read taps at
// col+dx (correct only for the old x = col-1 mapping) -> h1 shifted one
// column -> pool-average mostly cancelled it -> absmax 7.8e-3 (just over).
// Fix: taps at (col-1)+dx.
// Structure (unchanged from R9):
//   - w2 pre-transposed to [c*9+t][32 o]; per-lane o = lane&31; 9 coalesced
//     global_load_dword per c (vmcnt path, prefetched one c ahead) -- weights
//     no longer touch the SMEM/lgkmcnt drain path
//   - activations: wave-broadcast ds_read_b128 (2 distinct addrs/wave),
//     immediate offsets; in-order DS -> partial lgkm waits
//   - thread = (row r=wid, half, o): 32 positions x 1 output, acc[4][8]
//   - a2 fp16 (verified R8, absmax 9.8e-4)

#define BATCH 256
#define HW 4096

// ---------------- Kernel 0: transpose w2 -> [c*9+t][o] ----------------------
__global__ void k_prep(const float* __restrict__ w2, float* __restrict__ w2t) {
  int idx = blockIdx.x * 256 + threadIdx.x;  // 4608 total
  if (idx < 4608) {
    int o = idx & 31, ct = idx >> 5;  // ct = c*9+t
    w2t[idx] = w2[o * 144 + ct];
  }
}

// ---------------- Kernel 1: layer-1 stats (sum, sumsq per channel) ----------
__global__ __launch_bounds__(256) void k_stats1(const float* __restrict__ x,
                                                const float* __restrict__ w1,
                                                double* __restrict__ s1) {
  __shared__ float sx[66 * 66];
  __shared__ float red[4 * 16 * 2];
  int b = blockIdx.x, tid = threadIdx.x;
  const float* xb = x + b * HW;
  for (int i = tid; i < 66 * 66; i += 256) {
    int r = i / 66, cc = i - r * 66;
    int ry = r - 1, rx = cc - 1;
    sx[i] = (ry >= 0 && ry < 64 && rx >= 0 && rx < 64) ? xb[ry * 64 + rx] : 0.f;
  }
  __syncthreads();
  float tsum[16], tsq[16];
#pragma unroll
  for (int c = 0; c < 16; c++) { tsum[c] = 0.f; tsq[c] = 0.f; }
  for (int g = 0; g < 2; g++) {
    float wv[8][9];
#pragma unroll
    for (int c = 0; c < 8; c++)
#pragma unroll
      for (int t = 0; t < 9; t++) wv[c][t] = w1[(g * 8 + c) * 9 + t];
    for (int p = 0; p < 16; p++) {
      int pix = tid + p * 256;
      int y = pix >> 6, xx = pix & 63;
      float pa[9];
#pragma unroll
      for (int dy = 0; dy < 3; dy++)
#pragma unroll
        for (int dx = 0; dx < 3; dx++)
          pa[dy * 3 + dx] = sx[(y + dy) * 66 + xx + dx];
#pragma unroll
      for (int c = 0; c < 8; c++) {
        float acc = 0.f;
#pragma unroll
        for (int t = 0; t < 9; t++) acc += fabsf(pa[t] - wv[c][t]);
        float v = -acc;
        tsum[g * 8 + c] += v;
        tsq[g * 8 + c] += v * v;
      }
    }
  }
  int lane = tid & 63, wid = tid >> 6;
#pragma unroll
  for (int c = 0; c < 16; c++) {
    float s = tsum[c], q = tsq[c];
    for (int off = 32; off; off >>= 1) {
      s += __shfl_down(s, off, 64);
      q += __shfl_down(q, off, 64);
    }
    if (lane == 0) { red[(wid * 16 + c) * 2] = s; red[(wid * 16 + c) * 2 + 1] = q; }
  }
  __syncthreads();
  if (tid < 16) {
    float s = red[tid * 2] + red[(16 + tid) * 2] + red[(32 + tid) * 2] + red[(48 + tid) * 2];
    float q = red[tid * 2 + 1] + red[(16 + tid) * 2 + 1] + red[(32 + tid) * 2 + 1] +
              red[(48 + tid) * 2 + 1];
    atomicAdd(&s1[tid], (double)s);
    atomicAdd(&s1[16 + tid], (double)q);
  }
}

// ---------------- Kernel 2: layer 2 (the heavy one) -------------------------
// Block = (image b, 4-row band). Stage 1: h1 tile (6 rows x 68 cols, x=col-2,
// 16B aligned) into LDS. Stage 2: thread = (row r=wid, half=(lane>>5),
// o=lane&31); 4 sub-blocks of 8 positions; weights per-lane via global loads.
__global__ __launch_bounds__(256, 5) void k_layer2(
    const float* __restrict__ x, const float* __restrict__ w1,
    const double* __restrict__ s1, const float* __restrict__ g1,
    const float* __restrict__ b1, const float* __restrict__ w2t,
    __half* __restrict__ a2, double* __restrict__ s2) {
  __shared__ float sxt[8 * 68];        // x rows y0-2..y0+5, cols -2..65
  __shared__ float sh[16 * 6 * 68];    // h1 [c][6 rows: y0-1..y0+4][col: x=-2..65]
  __shared__ float red[4 * 64];        // per-wave (s[32], q[32])
  __shared__ float sc1s[16], sf1s[16];
  int blk = blockIdx.x;
  int b = blk >> 4, rb = blk & 15;
  int y0 = rb * 4;
  int tid = threadIdx.x;

  if (tid < 16) {  // inline BN1 params (block-redundant)
    double N = 1048576.0;
    double mean = s1[tid] / N;
    double var = s1[16 + tid] / N - mean * mean;
    float inv = (float)(1.0 / sqrt(var + 1e-5));
    float sc = g1[tid] * inv;
    sc1s[tid] = sc;
    sf1s[tid] = b1[tid] - (float)mean * sc;
  }
  const float* xb = x + b * HW;
  for (int i = tid; i < 8 * 68; i += 256) {
    int r = i / 68, cc = i - r * 68;
    int ry = y0 + r - 2, rx = cc - 2;
    sxt[i] = (ry >= 0 && ry < 64 && rx >= 0 && rx < 64) ? xb[ry * 64 + rx] : 0.f;
  }
  __syncthreads();
  // h1 recompute (same summation order as k_stats1 -> consistent values).
  // Tile col j holds x = j-2, so conv taps for x are sxt cols (j-1)+dx.
  for (int c = 0; c < 16; c++) {
    float wv[9];
#pragma unroll
    for (int t = 0; t < 9; t++) wv[t] = w1[c * 9 + t];
    float sc = sc1s[c], sf = sf1s[c];
    for (int i = tid; i < 408; i += 256) {
      int r = i / 68, col = i - r * 68;
      int y = y0 + r - 1, xx = col - 2;   // col 0..67 -> x -2..65
      float v = 0.f;  // h1 padding is post-activation zero
      if (y >= 0 && y < 64 && xx >= 0 && xx < 64) {
        float acc = 0.f;
#pragma unroll
        for (int dy = 0; dy < 3; dy++)
#pragma unroll
          for (int dx = 0; dx < 3; dx++)
            acc += fabsf(sxt[(r + dy) * 68 + (col - 1) + dx] - wv[dy * 3 + dx]);
        v = fmaxf(fmaf(-acc, sc, sf), 0.f);
      }
      sh[c * 408 + i] = v;
    }
  }
  __syncthreads();

  int lane = tid & 63, wid = tid >> 6;
  int r = wid;               // row within band (one per wave)
  int half = lane >> 5;      // 0: cols 0-31, 1: cols 32-63
  int o = lane & 31;         // this thread's output channel
  const float* shbase = &sh[r * 68 + half * 32];  // window col base (x0-2)
  const float* wbase = w2t + o;

  float acc[4][8];
#pragma unroll
  for (int sb = 0; sb < 4; sb++)
#pragma unroll
    for (int k = 0; k < 8; k++) acc[sb][k] = 0.f;

  // prefetch weights for c=0 (vmcnt path)
  float wn[9];
#pragma unroll
  for (int t = 0; t < 9; t++) wn[t] = wbase[t * 32];

#pragma unroll 1
  for (int c = 0; c < 16; c++) {
    float wc[9];
#pragma unroll
    for (int t = 0; t < 9; t++) wc[t] = wn[t];
    if (c < 15) {  // issue next-c weight loads (vmcnt, independent of DS)
      const float* np = wbase + (c + 1) * 288;
#pragma unroll
      for (int t = 0; t < 9; t++) wn[t] = np[t * 32];
    }
    const float* shc = shbase + c * 408;
#pragma unroll
    for (int sb = 0; sb < 4; sb++) {
      // 12-float window per dy row: x = x0-2 .. x0+9, 16B-aligned
      float A[3][12];
#pragma unroll
      for (int dy = 0; dy < 3; dy++) {
        const float* rp = shc + dy * 68 + sb * 8;
        float4 q0 = *(const float4*)rp;
        float4 q1 = *(const float4*)(rp + 4);
        float4 q2 = *(const float4*)(rp + 8);
        A[dy][0] = q0.x; A[dy][1] = q0.y; A[dy][2] = q0.z; A[dy][3] = q0.w;
        A[dy][4] = q1.x; A[dy][5] = q1.y; A[dy][6] = q1.z; A[dy][7] = q1.w;
        A[dy][8] = q2.x; A[dy][9] = q2.y; A[dy][10] = q2.z; A[dy][11] = q2.w;
      }
#pragma unroll
      for (int dy = 0; dy < 3; dy++) {
        float w0 = wc[dy * 3], w1v = wc[dy * 3 + 1], w2v = wc[dy * 3 + 2];
#pragma unroll
        for (int k = 0; k < 8; k++)
          acc[sb][k] += fabsf(A[dy][k + 1] - w0) + fabsf(A[dy][k + 2] - w1v) +
                        fabsf(A[dy][k + 3] - w2v);
      }
    }
  }

  // epilogue: fp16 store + per-o stats
  __half* a2p = a2 + ((size_t)b * 32 + o) * HW + (y0 + r) * 64 + half * 32;
  float s = 0.f, q = 0.f;
#pragma unroll
  for (int sb = 0; sb < 4; sb++) {
    __half2 hv[4];
#pragma unroll
    for (int k = 0; k < 4; k++) {
      float v0 = -acc[sb][2 * k], v1 = -acc[sb][2 * k + 1];
      s += v0 + v1;
      q += v0 * v0 + v1 * v1;
      hv[k] = __halves2half2(__float2half_rn(v0), __float2half_rn(v1));
    }
    *(float4*)(a2p + sb * 8) = *(float4*)hv;
  }
  // combine the two halves (lane ^ 32 has same o)
  s += __shfl_xor(s, 32, 64);
  q += __shfl_xor(q, 32, 64);
  if (lane < 32) { red[wid * 64 + o] = s; red[wid * 64 + 32 + o] = q; }
  __syncthreads();
  if (tid < 32) {
    float ss = red[tid] + red[64 + tid] + red[128 + tid] + red[192 + tid];
    float qq = red[32 + tid] + red[96 + tid] + red[160 + tid] + red[224 + tid];
    atomicAdd(&s2[tid], (double)ss);
    atomicAdd(&s2[32 + tid], (double)qq);
  }
}

// ---------------- Kernel 3: BN2 (inline params) + ReLU + avgpool + FC -------
__global__ __launch_bounds__(1024) void k_poolfc(const __half* __restrict__ a2,
                                                 const double* __restrict__ s2,
                                                 const float* __restrict__ g2,
                                                 const float* __restrict__ b2,
                                                 const float* __restrict__ fw,
                                                 const float* __restrict__ fb,
                                                 float* __restrict__ out) {
  __shared__ float poolv[32];
  int b = blockIdx.x, tid = threadIdx.x;
  int o = tid >> 5, part = tid & 31;  // 32 threads per channel
  double N = 1048576.0;
  double mean = s2[o] / N;
  double var = s2[32 + o] / N - mean * mean;
  float s = g2[o] * (float)(1.0 / sqrt(var + 1e-5));
  float f = b2[o] - (float)mean * s;
  const float4* p = (const float4*)(a2 + ((size_t)b * 32 + o) * HW);
  float acc = 0.f;
#pragma unroll
  for (int i = 0; i < 16; i++) {  // 16 iters * 32 threads * 8 halves = 4096
    float4 raw = p[i * 32 + part];
    const __half2* hp = (const __half2*)&raw;
#pragma unroll
    for (int k = 0; k < 4; k++) {
      float2 v = __half22float2(hp[k]);
      acc += fmaxf(fmaf(v.x, s, f), 0.f) + fmaxf(fmaf(v.y, s, f), 0.f);
    }
  }
  acc += __shfl_down(acc, 16, 32);
  acc += __shfl_down(acc, 8, 32);
  acc += __shfl_down(acc, 4, 32);
  acc += __shfl_down(acc, 2, 32);
  acc += __shfl_down(acc, 1, 32);
  if (part == 0) poolv[o] = acc * (1.f / 4096.f);
  __syncthreads();
  if (tid < 10) {
    float rr = fb[tid];
#pragma unroll
    for (int oc = 0; oc < 32; oc++) rr += poolv[oc] * fw[tid * 32 + oc];
    out[b * 10 + tid] = rr;
  }
}

extern "C" void kernel_launch(void* const* d_in, const int* in_sizes, int n_in,
                              void* d_out, int out_size, void* d_ws, size_t ws_size,
                              hipStream_t stream) {
  const float* x   = (const float*)d_in[0];
  const float* w1  = (const float*)d_in[1];
  const float* g1  = (const float*)d_in[2];
  const float* b1  = (const float*)d_in[3];
  const float* w2  = (const float*)d_in[4];
  const float* g2  = (const float*)d_in[5];
  const float* b2  = (const float*)d_in[6];
  const float* fcw = (const float*)d_in[7];
  const float* fcb = (const float*)d_in[8];
  float* out = (float*)d_out;

  char* ws = (char*)d_ws;
  __half* a2 = (__half*)ws;                                // 67,108,864 B
  double* stats = (double*)(ws + 67108864);                // 96 doubles
  double* s1 = stats;                                      // sum[16], sq[16]
  double* s2 = stats + 32;                                 // sum[32], sq[32]
  float* w2t = (float*)(ws + 67108864 + 768);              // 4608 floats

  hipMemsetAsync(stats, 0, 768, stream);
  k_prep<<<18, 256, 0, stream>>>(w2, w2t);
  k_stats1<<<256, 256, 0, stream>>>(x, w1, s1);
  k_layer2<<<4096, 256, 0, stream>>>(x, w1, s1, g1, b1, w2t, a2, s2);
  k_poolfc<<<256, 1024, 0, stream>>>(a2, s2, g2, b2, fcw, fcb, out);
}